// Round 5
// baseline (334.385 us; speedup 1.0000x reference)
//
#include <hip/hip_runtime.h>
#include <stdint.h>

typedef __attribute__((ext_vector_type(4))) float f32x4;
typedef __attribute__((ext_vector_type(8))) short short8;
typedef __attribute__((ext_vector_type(4))) unsigned short u16x4;

#define BB 4
#define TT 1024
#define CC 1024
#define HH 16
#define KSZ 31
#define PADL 15
#define RR 64
#define NL 496      // H*K
#define NP 512      // padded N for GEMM
#define MM 4096     // B*T

// round-to-nearest-even f32 -> bf16
__device__ __forceinline__ unsigned short f2bf(float f) {
    uint32_t u = __float_as_uint(f);
    u += 0x7FFFu + ((u >> 16) & 1u);
    return (unsigned short)(u >> 16);
}

__device__ __forceinline__ void gload_lds16(const void* g, void* l) {
    __builtin_amdgcn_global_load_lds(
        (const __attribute__((address_space(1))) unsigned int*)g,
        (__attribute__((address_space(3))) unsigned int*)l, 16, 0, 0);
}

// opaque zero: defeats cross-rep CSE/hoisting without runtime cost
__device__ __forceinline__ int opaque_zero() {
    int zr = 0;
    asm volatile("" : "+v"(zr));
    return zr;
}

// ---------------------------------------------------------------------------
// Kernel 1: cast X -> Xb (bf16), W -> Wb (bf16, zero-padded to 512 rows)
// ---------------------------------------------------------------------------
__global__ __launch_bounds__(256) void cast_kernel(const float* __restrict__ X,
                                                   const float* __restrict__ W,
                                                   unsigned short* __restrict__ Xb,
                                                   unsigned short* __restrict__ Wb,
                                                   int reps) {
    for (int rep = 0; rep < reps; ++rep) {
        const int i = blockIdx.x * 256 + threadIdx.x + opaque_zero();
        const int nx4 = MM * CC / 4;   // 1,048,576
        const int nw4 = NP * CC / 4;   // 131,072
        if (i < nx4) {
            f32x4 v = ((const f32x4*)X)[i];
            u16x4 o = { f2bf(v[0]), f2bf(v[1]), f2bf(v[2]), f2bf(v[3]) };
            ((u16x4*)Xb)[i] = o;
        } else if (i < nx4 + nw4) {
            const int j = i - nx4;
            const int n = j >> 8;
            u16x4 o = { 0, 0, 0, 0 };
            if (n < NL) {
                f32x4 v = ((const f32x4*)W)[j];
                o[0] = f2bf(v[0]); o[1] = f2bf(v[1]); o[2] = f2bf(v[2]); o[3] = f2bf(v[3]);
            }
            ((u16x4*)Wb)[j] = o;
        }
    }
}

// ---------------------------------------------------------------------------
// Kernel 2: bf16 MFMA GEMM, double-buffered.  LT[n][m] = sum_c Xb[m][c]*Wb[n][c]
// ---------------------------------------------------------------------------
__global__ __launch_bounds__(256) void gemm_mfma(const unsigned short* __restrict__ Xb,
                                                 const unsigned short* __restrict__ Wb,
                                                 float* __restrict__ LT,
                                                 int reps) {
    __shared__ unsigned short As[2 * 64 * 64];   // 2 x 8 KB
    __shared__ unsigned short Bs[2 * 64 * 64];   // 2 x 8 KB

    const int tid = threadIdx.x;
    const int lane = tid & 63;
    const int wv = tid >> 6;
    const int wm = wv >> 1, wn = wv & 1;           // 2x2 wave grid

    int bid = blockIdx.x;
    bid = (bid & 7) * 64 + (bid >> 3);             // XCD-contiguous chunks
    const int n0b = (bid & 7) * 64;
    const int m0b = (bid >> 3) * 64;

#define STAGE(ktt, bufsel) do {                                                  \
        const int k0s = (ktt) * 64;                                              \
        _Pragma("unroll")                                                        \
        for (int p = 0; p < 2; ++p) {                                            \
            const int c = p * 256 + tid;                                         \
            const int row = c >> 3, kcs = c & 7;                                 \
            const int kg = (kcs ^ (row & 7)) << 3;                               \
            gload_lds16(Xb + (size_t)(m0 + row) * CC + k0s + kg,                 \
                        (char*)As + (bufsel) * 8192 + c * 16);                   \
            gload_lds16(Wb + (size_t)(n0 + row) * CC + k0s + kg,                 \
                        (char*)Bs + (bufsel) * 8192 + c * 16);                   \
        }                                                                        \
    } while (0)

    for (int rep = 0; rep < reps; ++rep) {
        const int zr = opaque_zero();
        const int m0 = m0b + zr, n0 = n0b + zr;

        f32x4 acc[2][2] = {};
        int cur = 0;
        STAGE(0, 0);
        __syncthreads();

        for (int kt = 0; kt < CC / 64; ++kt) {
            if (kt + 1 < CC / 64) STAGE(kt + 1, cur ^ 1);   // prefetch next tile
            const char* Ab = (const char*)As + cur * 8192;
            const char* Bb = (const char*)Bs + cur * 8192;
#pragma unroll
            for (int ks = 0; ks < 2; ++ks) {
                short8 af[2], bfv[2];
                const int kc = ks * 4 + (lane >> 4);
#pragma unroll
                for (int s = 0; s < 2; ++s) {
                    const int ra = wm * 32 + s * 16 + (lane & 15);
                    af[s] = *(const short8*)(Ab + ra * 128 + ((kc ^ (ra & 7)) << 4));
                    const int rb = wn * 32 + s * 16 + (lane & 15);
                    bfv[s] = *(const short8*)(Bb + rb * 128 + ((kc ^ (rb & 7)) << 4));
                }
#pragma unroll
                for (int si = 0; si < 2; ++si)
#pragma unroll
                    for (int sj = 0; sj < 2; ++sj)
                        acc[si][sj] = __builtin_amdgcn_mfma_f32_16x16x32_bf16(
                            af[si], bfv[sj], acc[si][sj], 0, 0, 0);
            }
            __syncthreads();   // drains vmcnt(0): prefetched tile is ready
            cur ^= 1;
        }

        // epilogue: C/D layout col=lane&15 (n), row=(lane>>4)*4+reg (m) [m89]
        const int col = lane & 15, rbase = (lane >> 4) * 4;
#pragma unroll
        for (int si = 0; si < 2; ++si)
#pragma unroll
            for (int sj = 0; sj < 2; ++sj) {
                const int n = n0 + wn * 32 + sj * 16 + col;
                if (n < NL) {
                    const int m = m0 + wm * 32 + si * 16 + rbase;
                    *(f32x4*)&LT[(size_t)n * MM + m] = acc[si][sj];
                }
            }
        __syncthreads();
    }
#undef STAGE
}

// ---------------------------------------------------------------------------
// Kernel 3: fused softmax + depthwise band conv.  Block = (b, h, 64-t tile).
// ---------------------------------------------------------------------------
__global__ __launch_bounds__(256) void conv_fused(const float* __restrict__ X,
                                                  const float* __restrict__ LT,
                                                  float* __restrict__ out,
                                                  int reps) {
    __shared__ float xsT[64 * 100];   // 25.6 KB
    __shared__ float lsm[32 * 64];    //  8 KB
    __shared__ float wsm[64 * 36];    //  9 KB

    const int tid = threadIdx.x, lane = tid & 63, wv = tid >> 6;
    int bid = blockIdx.x;
    const int tt = bid & 15;
    const int h = (bid >> 4) & 15;
    const int b = bid >> 8;
    const int t0b = tt * 64;

    for (int rep = 0; rep < reps; ++rep) {
        __syncthreads();   // protect LDS overwrite vs previous rep's readers
        const int t0 = t0b + opaque_zero();

        // ---- stage x transposed (rows 94/95 zero; OOB t zero)
        for (int i = 0; i < 24; ++i) {
            const int row = i * 4 + wv;          // 0..95
            const int tg = t0 - PADL + row;
            float v = 0.f;
            if (row < 94 && tg >= 0 && tg < TT)
                v = X[(size_t)(b * TT + tg) * CC + h * RR + lane];
            const int tc = row >> 2;
            xsT[lane * 100 + ((tc ^ (lane & 7)) << 2) + (row & 3)] = v;
        }
        // ---- stage logits k-major: coalesced 256B per (wave,k)
#pragma unroll
        for (int i = 0; i < 8; ++i) {
            const int kk = wv * 8 + i;
            if (kk < KSZ)
                lsm[kk * 64 + lane] = LT[(size_t)(h * KSZ + kk) * MM + b * TT + t0 + lane];
        }
        __syncthreads();

        // ---- softmax: 4 lanes per t, shfl_xor reduce
        {
            const int j = lane & 3, tl = wv * 16 + (lane >> 2);
            float v[8];
            float mx = -1e30f;
#pragma unroll
            for (int i = 0; i < 8; ++i) {
                const int kk = j * 8 + i;
                v[i] = (kk < KSZ) ? lsm[kk * 64 + tl] : -1e30f;
                mx = fmaxf(mx, v[i]);
            }
            mx = fmaxf(mx, __shfl_xor(mx, 1));
            mx = fmaxf(mx, __shfl_xor(mx, 2));
            float s = 0.f;
#pragma unroll
            for (int i = 0; i < 8; ++i) { v[i] = __expf(v[i] - mx); s += v[i]; }
            s += __shfl_xor(s, 1);
            s += __shfl_xor(s, 2);
            const float inv = 1.f / s;
#pragma unroll
            for (int i = 0; i < 8; ++i)
                wsm[tl * 36 + j * 8 + i] = v[i] * inv;
        }
        __syncthreads();

        // ---- depthwise conv: 2 groups of 8 t per lane
#pragma unroll
        for (int g = 0; g < 2; ++g) {
            const int gl = wv * 16 + g * 8;
            f32x4 xw[10];
#pragma unroll
            for (int q = 0; q < 10; ++q) {
                const int tc = (gl >> 2) + q;
                xw[q] = *(const f32x4*)&xsT[lane * 100 + ((tc ^ (lane & 7)) << 2)];
            }
            float acc[8] = {};
#pragma unroll
            for (int tl8 = 0; tl8 < 8; ++tl8) {
                const float* wp = &wsm[(gl + tl8) * 36];
#pragma unroll
                for (int kq = 0; kq < 8; ++kq) {
                    const f32x4 w4 = *(const f32x4*)(wp + kq * 4);  // uniform broadcast
#pragma unroll
                    for (int jj = 0; jj < 4; ++jj) {
                        const int e = tl8 + kq * 4 + jj;            // static index
                        acc[tl8] = fmaf(w4[jj], xw[e >> 2][e & 3], acc[tl8]);
                    }
                }
            }
#pragma unroll
            for (int tl8 = 0; tl8 < 8; ++tl8)
                out[(size_t)(b * TT + t0 + gl + tl8) * CC + h * RR + lane] = acc[tl8];
        }
    }
}

// ---------------------------------------------------------------------------
extern "C" void kernel_launch(void* const* d_in, const int* in_sizes, int n_in,
                              void* d_out, int out_size, void* d_ws, size_t ws_size,
                              hipStream_t stream) {
    const float* x = (const float*)d_in[0];
    const float* W = (const float*)d_in[1];
    float* out = (float*)d_out;
    char* ws = (char*)d_ws;

    unsigned short* Xb = (unsigned short*)ws;                          // 8,388,608 B
    unsigned short* Wb = (unsigned short*)(ws + 8388608);              // 1,048,576 B
    float* LT = (float*)(ws + 9437184);                                // 8,126,464 B

    const int REPS = 8;   // diagnostic amplification — every rep does identical work

    cast_kernel<<<(MM * CC / 4 + NP * CC / 4 + 255) / 256, 256, 0, stream>>>(x, W, Xb, Wb, REPS);
    gemm_mfma<<<NP / 64 * (MM / 64), 256, 0, stream>>>(Xb, Wb, LT, REPS);
    conv_fused<<<BB * HH * (TT / 64), 256, 0, stream>>>(x, LT, out, REPS);
}

// Round 6
// 98.144 us; speedup vs baseline: 3.4071x; 3.4071x over previous
//
#include <hip/hip_runtime.h>
#include <stdint.h>

typedef __attribute__((ext_vector_type(4))) float f32x4;
typedef __attribute__((ext_vector_type(8))) short short8;
typedef __attribute__((ext_vector_type(4))) unsigned short u16x4;

#define BB 4
#define TT 1024
#define CC 1024
#define HH 16
#define KSZ 31
#define PADL 15
#define RR 64
#define NL 496      // H*K
#define NP 512      // padded N for GEMM
#define MM 4096     // B*T

// round-to-nearest-even f32 -> bf16
__device__ __forceinline__ unsigned short f2bf(float f) {
    uint32_t u = __float_as_uint(f);
    u += 0x7FFFu + ((u >> 16) & 1u);
    return (unsigned short)(u >> 16);
}

__device__ __forceinline__ void gload_lds16(const void* g, void* l) {
    __builtin_amdgcn_global_load_lds(
        (const __attribute__((address_space(1))) unsigned int*)g,
        (__attribute__((address_space(3))) unsigned int*)l, 16, 0, 0);
}

// opaque zero: defeats cross-rep CSE/hoisting without runtime cost
__device__ __forceinline__ int opaque_zero() {
    int zr = 0;
    asm volatile("" : "+v"(zr));
    return zr;
}

// ---------------------------------------------------------------------------
// Kernel 1: cast X -> Xb (bf16), W -> Wb (bf16, zero-padded to 512 rows)
// ---------------------------------------------------------------------------
__global__ __launch_bounds__(256) void cast_kernel(const float* __restrict__ X,
                                                   const float* __restrict__ W,
                                                   unsigned short* __restrict__ Xb,
                                                   unsigned short* __restrict__ Wb,
                                                   int reps) {
    for (int rep = 0; rep < reps; ++rep) {
        const int i = blockIdx.x * 256 + threadIdx.x + opaque_zero();
        const int nx4 = MM * CC / 4;   // 1,048,576
        const int nw4 = NP * CC / 4;   // 131,072
        if (i < nx4) {
            f32x4 v = ((const f32x4*)X)[i];
            u16x4 o = { f2bf(v[0]), f2bf(v[1]), f2bf(v[2]), f2bf(v[3]) };
            ((u16x4*)Xb)[i] = o;
        } else if (i < nx4 + nw4) {
            const int j = i - nx4;
            const int n = j >> 8;
            u16x4 o = { 0, 0, 0, 0 };
            if (n < NL) {
                f32x4 v = ((const f32x4*)W)[j];
                o[0] = f2bf(v[0]); o[1] = f2bf(v[1]); o[2] = f2bf(v[2]); o[3] = f2bf(v[3]);
            }
            ((u16x4*)Wb)[j] = o;
        }
    }
}

// ---------------------------------------------------------------------------
// Kernel 2: bf16 MFMA GEMM, double-buffered.  LT[n][m] = sum_c Xb[m][c]*Wb[n][c]
// 64x64 tile, BK=64, 4 waves (2x2, each 32x32), global_load_lds + XOR swizzle.
// ---------------------------------------------------------------------------
__global__ __launch_bounds__(256) void gemm_mfma(const unsigned short* __restrict__ Xb,
                                                 const unsigned short* __restrict__ Wb,
                                                 float* __restrict__ LT,
                                                 int reps) {
    __shared__ unsigned short As[2 * 64 * 64];   // 2 x 8 KB
    __shared__ unsigned short Bs[2 * 64 * 64];   // 2 x 8 KB

    const int tid = threadIdx.x;
    const int lane = tid & 63;
    const int wv = tid >> 6;
    const int wm = wv >> 1, wn = wv & 1;           // 2x2 wave grid

    int bid = blockIdx.x;
    bid = (bid & 7) * 64 + (bid >> 3);             // XCD-contiguous chunks
    const int n0b = (bid & 7) * 64;
    const int m0b = (bid >> 3) * 64;

#define STAGE(ktt, bufsel) do {                                                  \
        const int k0s = (ktt) * 64;                                              \
        _Pragma("unroll")                                                        \
        for (int p = 0; p < 2; ++p) {                                            \
            const int c = p * 256 + tid;                                         \
            const int row = c >> 3, kcs = c & 7;                                 \
            const int kg = (kcs ^ (row & 7)) << 3;                               \
            gload_lds16(Xb + (size_t)(m0 + row) * CC + k0s + kg,                 \
                        (char*)As + (bufsel) * 8192 + c * 16);                   \
            gload_lds16(Wb + (size_t)(n0 + row) * CC + k0s + kg,                 \
                        (char*)Bs + (bufsel) * 8192 + c * 16);                   \
        }                                                                        \
    } while (0)

    for (int rep = 0; rep < reps; ++rep) {
        const int zr = opaque_zero();
        const int m0 = m0b + zr, n0 = n0b + zr;

        f32x4 acc[2][2] = {};
        int cur = 0;
        STAGE(0, 0);
        __syncthreads();

        for (int kt = 0; kt < CC / 64; ++kt) {
            if (kt + 1 < CC / 64) STAGE(kt + 1, cur ^ 1);   // prefetch next tile
            const char* Ab = (const char*)As + cur * 8192;
            const char* Bb = (const char*)Bs + cur * 8192;
#pragma unroll
            for (int ks = 0; ks < 2; ++ks) {
                short8 af[2], bfv[2];
                const int kc = ks * 4 + (lane >> 4);
#pragma unroll
                for (int s = 0; s < 2; ++s) {
                    const int ra = wm * 32 + s * 16 + (lane & 15);
                    af[s] = *(const short8*)(Ab + ra * 128 + ((kc ^ (ra & 7)) << 4));
                    const int rb = wn * 32 + s * 16 + (lane & 15);
                    bfv[s] = *(const short8*)(Bb + rb * 128 + ((kc ^ (rb & 7)) << 4));
                }
#pragma unroll
                for (int si = 0; si < 2; ++si)
#pragma unroll
                    for (int sj = 0; sj < 2; ++sj)
                        acc[si][sj] = __builtin_amdgcn_mfma_f32_16x16x32_bf16(
                            af[si], bfv[sj], acc[si][sj], 0, 0, 0);
            }
            __syncthreads();   // drains vmcnt(0): prefetched tile is ready
            cur ^= 1;
        }

        // epilogue: C/D layout col=lane&15 (n), row=(lane>>4)*4+reg (m) [m89]
        const int col = lane & 15, rbase = (lane >> 4) * 4;
#pragma unroll
        for (int si = 0; si < 2; ++si)
#pragma unroll
            for (int sj = 0; sj < 2; ++sj) {
                const int n = n0 + wn * 32 + sj * 16 + col;
                if (n < NL) {
                    const int m = m0 + wm * 32 + si * 16 + rbase;
                    *(f32x4*)&LT[(size_t)n * MM + m] = acc[si][sj];
                }
            }
        __syncthreads();
    }
#undef STAGE
}

// ---------------------------------------------------------------------------
// Kernel 3: fused softmax + depthwise band conv, register-window version.
// Block = (b, h, 64-t tile); 4 waves x 16 t; lane = r.
// - x window: 46 coalesced global rows -> 47 VGPRs per lane (static indexing)
// - softmax: logits direct from global LT (L2-resident), 4 lanes per t,
//   shfl_xor reduce; normalized weights -> wsm stride 36 (9 quads, odd ->
//   conflict-free b128 writes), read back as uniform b128 broadcasts.
// - LDS total 9.2 KB, zero x-traffic, ~0 bank conflicts.
// ---------------------------------------------------------------------------
__global__ __launch_bounds__(256) void conv_fused(const float* __restrict__ X,
                                                  const float* __restrict__ LT,
                                                  float* __restrict__ out,
                                                  int reps) {
    __shared__ float wsm[64 * 36];   // 9,216 B

    const int tid = threadIdx.x, lane = tid & 63, wv = tid >> 6;
    int bid = blockIdx.x;
    const int tt = bid & 15;
    const int h = (bid >> 4) & 15;
    const int b = bid >> 8;
    const int T0 = tt * 64;
    const int tlo = T0 + wv * 16 - PADL;   // first x row this wave needs

    for (int rep = 0; rep < reps; ++rep) {
        const int zr = opaque_zero();

        // ---- x window into registers: rows tlo .. tlo+45 (uniform guards)
        float xr[47];
#pragma unroll
        for (int rI = 0; rI < 46; ++rI) {
            const int tg = tlo + rI + zr;
            xr[rI] = ((unsigned)tg < TT)
                       ? X[(size_t)(b * TT + tg) * CC + h * RR + lane] : 0.f;
        }
        xr[46] = 0.f;   // pad so k=31 term (weight 0) stays in range

        // ---- softmax: 4 lanes per t (j = lane&3 covers k = 8j..8j+7)
        const int j = lane & 3, a = lane >> 2;
        const int tl = wv * 16 + a;              // t within 64-tile
        const int m = b * TT + T0 + tl;          // global row index
        float v[8];
        float mx = -1e30f;
#pragma unroll
        for (int i = 0; i < 8; ++i) {
            const int kk = j * 8 + i;
            float lv = -1e30f;
            if (kk < KSZ) lv = LT[(size_t)(h * KSZ + kk) * MM + m];
            v[i] = lv; mx = fmaxf(mx, lv);
        }
        mx = fmaxf(mx, __shfl_xor(mx, 1));
        mx = fmaxf(mx, __shfl_xor(mx, 2));
        float s = 0.f;
#pragma unroll
        for (int i = 0; i < 8; ++i) { v[i] = __expf(v[i] - mx); s += v[i]; }
        s += __shfl_xor(s, 1);
        s += __shfl_xor(s, 2);
        const float inv = 1.f / s;
        f32x4 wlo = { v[0] * inv, v[1] * inv, v[2] * inv, v[3] * inv };
        f32x4 whi = { v[4] * inv, v[5] * inv, v[6] * inv, v[7] * inv };
        // stride 36 floats = 9 quads (odd) -> consecutive-8-lane groups hit
        // 8 distinct bank-quads on both b128 writes: conflict-free
        *(f32x4*)&wsm[tl * 36 + j * 8] = wlo;
        *(f32x4*)&wsm[tl * 36 + j * 8 + 4] = whi;
        __syncthreads();

        // ---- conv: 16 t per lane, all-register x, broadcast w
        float acc[16];
#pragma unroll
        for (int t8 = 0; t8 < 16; ++t8) acc[t8] = 0.f;
#pragma unroll
        for (int t8 = 0; t8 < 16; ++t8) {
            const float* wp = &wsm[(wv * 16 + t8) * 36];
#pragma unroll
            for (int kq = 0; kq < 8; ++kq) {
                const f32x4 w4 = *(const f32x4*)(wp + kq * 4);  // uniform broadcast
#pragma unroll
                for (int jj = 0; jj < 4; ++jj)
                    acc[t8] = fmaf(w4[jj], xr[t8 + kq * 4 + jj], acc[t8]);
            }
        }
#pragma unroll
        for (int t8 = 0; t8 < 16; ++t8)
            out[(size_t)(b * TT + T0 + wv * 16 + t8) * CC + h * RR + lane] = acc[t8];
        __syncthreads();   // protect wsm before next rep
    }
}

// ---------------------------------------------------------------------------
extern "C" void kernel_launch(void* const* d_in, const int* in_sizes, int n_in,
                              void* d_out, int out_size, void* d_ws, size_t ws_size,
                              hipStream_t stream) {
    const float* x = (const float*)d_in[0];
    const float* W = (const float*)d_in[1];
    float* out = (float*)d_out;
    char* ws = (char*)d_ws;

    unsigned short* Xb = (unsigned short*)ws;                          // 8,388,608 B
    unsigned short* Wb = (unsigned short*)(ws + 8388608);              // 1,048,576 B
    float* LT = (float*)(ws + 9437184);                                // 8,126,464 B

    const int REPS = 1;

    cast_kernel<<<(MM * CC / 4 + NP * CC / 4 + 255) / 256, 256, 0, stream>>>(x, W, Xb, Wb, REPS);
    gemm_mfma<<<NP / 64 * (MM / 64), 256, 0, stream>>>(Xb, Wb, LT, REPS);
    conv_fused<<<BB * HH * (TT / 64), 256, 0, stream>>>(x, LT, out, REPS);
}

// Round 7
// 92.984 us; speedup vs baseline: 3.5962x; 1.0555x over previous
//
#include <hip/hip_runtime.h>
#include <stdint.h>

typedef __attribute__((ext_vector_type(4))) float f32x4;
typedef __attribute__((ext_vector_type(8))) short short8;
typedef __attribute__((ext_vector_type(4))) unsigned short u16x4;

#define BB 4
#define TT 1024
#define CC 1024
#define HH 16
#define KSZ 31
#define PADL 15
#define RR 64
#define NL 496      // H*K
#define NP 512      // padded N for GEMM
#define MM 4096     // B*T

// round-to-nearest-even f32 -> bf16
__device__ __forceinline__ unsigned short f2bf(float f) {
    uint32_t u = __float_as_uint(f);
    u += 0x7FFFu + ((u >> 16) & 1u);
    return (unsigned short)(u >> 16);
}

// ---------------------------------------------------------------------------
// Kernel 1: fused cast+GEMM, double-buffered reg-staging.
//   LT[n][m] = sum_c bf16(X[m][c]) * bf16(W[n][c])
// 64x64 tile, BK=64, 4 waves (2x2, each 32x32).
// Staging: global f32x4 -> RNE cvt -> ds_write_b64 bf16 with the same
// 16B-granule XOR swizzle involution the fragment reads expect
// (granule g of row r stored at position g ^ (r&7)).
// T14 split: issue next tile's loads BEFORE compute, ds_write after,
// one barrier per K-step (write target buf^1 disjoint from read buf).
// Grid 512 = 0 mod 8 -> bijective XCD swizzle: XCD x owns m-rows
// [x*512, (x+1)*512) over all n-panels => X rows L2-resident per XCD.
// ---------------------------------------------------------------------------
__global__ __launch_bounds__(256) void gemm_fused(const float* __restrict__ X,
                                                  const float* __restrict__ W,
                                                  float* __restrict__ LT) {
    __shared__ unsigned short As[2 * 64 * 64];   // 2 x 8 KB
    __shared__ unsigned short Bs[2 * 64 * 64];   // 2 x 8 KB

    const int tid = threadIdx.x;
    const int lane = tid & 63;
    const int wv = tid >> 6;
    const int wm = wv >> 1, wn = wv & 1;           // 2x2 wave grid

    int bid = blockIdx.x;
    bid = (bid & 7) * 64 + (bid >> 3);             // XCD-contiguous chunks
    const int n0 = (bid & 7) * 64;
    const int m0 = (bid >> 3) * 64;

    // per-thread staging geometry: 4 chunks of f32x4 each for A and B
    // chunk ch = p*256+tid: row = ch>>4 (0..63), cc = ch&15 (float4 col)
    // LDS byte addr = row*128 + ((g ^ (row&7))<<4) + (half<<3), g=cc>>1
    int srow[4], saddr[4];
#pragma unroll
    for (int p = 0; p < 4; ++p) {
        const int ch = p * 256 + tid;
        const int row = ch >> 4, cc = ch & 15;
        srow[p] = row;
        saddr[p] = row * 128 + ((((cc >> 1) ^ (row & 7)) << 4) + ((cc & 1) << 3));
    }

#define LOADV(ktt, av, bv) do {                                                  \
        const int k0s = (ktt) * 64;                                              \
        _Pragma("unroll")                                                        \
        for (int p = 0; p < 4; ++p) {                                            \
            const int ch = p * 256 + tid;                                        \
            const int cc = ch & 15;                                              \
            av[p] = *(const f32x4*)&X[(size_t)(m0 + srow[p]) * CC + k0s + cc * 4]; \
            const int n = n0 + srow[p];                                          \
            bv[p] = (n < NL) ? *(const f32x4*)&W[(size_t)n * CC + k0s + cc * 4]  \
                             : f32x4{0.f, 0.f, 0.f, 0.f};                        \
        }                                                                        \
    } while (0)

#define WRITEV(av, bv, bufsel) do {                                              \
        _Pragma("unroll")                                                        \
        for (int p = 0; p < 4; ++p) {                                            \
            u16x4 ao = { f2bf(av[p][0]), f2bf(av[p][1]),                         \
                         f2bf(av[p][2]), f2bf(av[p][3]) };                       \
            u16x4 bo = { f2bf(bv[p][0]), f2bf(bv[p][1]),                         \
                         f2bf(bv[p][2]), f2bf(bv[p][3]) };                       \
            *(u16x4*)((char*)As + (bufsel) * 8192 + saddr[p]) = ao;              \
            *(u16x4*)((char*)Bs + (bufsel) * 8192 + saddr[p]) = bo;              \
        }                                                                        \
    } while (0)

    f32x4 acc[2][2] = {};
    {
        f32x4 a0[4], b0[4];
        LOADV(0, a0, b0);
        WRITEV(a0, b0, 0);
    }
    __syncthreads();

    int cur = 0;
    for (int kt = 0; kt < CC / 64; ++kt) {
        f32x4 an[4], bn[4];
        if (kt + 1 < CC / 64) LOADV(kt + 1, an, bn);   // issue early

        const char* Ab = (const char*)As + cur * 8192;
        const char* Bb = (const char*)Bs + cur * 8192;
#pragma unroll
        for (int ks = 0; ks < 2; ++ks) {
            short8 af[2], bfv[2];
            const int kc = ks * 4 + (lane >> 4);
#pragma unroll
            for (int s = 0; s < 2; ++s) {
                const int ra = wm * 32 + s * 16 + (lane & 15);
                af[s] = *(const short8*)(Ab + ra * 128 + ((kc ^ (ra & 7)) << 4));
                const int rb = wn * 32 + s * 16 + (lane & 15);
                bfv[s] = *(const short8*)(Bb + rb * 128 + ((kc ^ (rb & 7)) << 4));
            }
#pragma unroll
            for (int si = 0; si < 2; ++si)
#pragma unroll
                for (int sj = 0; sj < 2; ++sj)
                    acc[si][sj] = __builtin_amdgcn_mfma_f32_16x16x32_bf16(
                        af[si], bfv[sj], acc[si][sj], 0, 0, 0);
        }

        if (kt + 1 < CC / 64) WRITEV(an, bn, cur ^ 1); // write-late, disjoint buf
        __syncthreads();
        cur ^= 1;
    }
#undef LOADV
#undef WRITEV

    // epilogue: C/D layout col=lane&15 (n), row=(lane>>4)*4+reg (m) [m89]
    const int col = lane & 15, rbase = (lane >> 4) * 4;
#pragma unroll
    for (int si = 0; si < 2; ++si)
#pragma unroll
        for (int sj = 0; sj < 2; ++sj) {
            const int n = n0 + wn * 32 + sj * 16 + col;
            if (n < NL) {
                const int m = m0 + wm * 32 + si * 16 + rbase;
                *(f32x4*)&LT[(size_t)n * MM + m] = acc[si][sj];
            }
        }
}

// ---------------------------------------------------------------------------
// Kernel 2: fused softmax + depthwise band conv, register-window version.
// Block = (b, h, 64-t tile); 4 waves x 16 t; lane = r.
// - x window: 46 coalesced global rows -> 47 VGPRs per lane (static indexing)
// - softmax: logits direct from global LT (L2/L3-resident), 4 lanes per t,
//   shfl_xor reduce; normalized weights -> wsm stride 36 (conflict-free b128)
// - LDS 9.2 KB, zero x LDS traffic, ~0 bank conflicts.
// ---------------------------------------------------------------------------
__global__ __launch_bounds__(256) void conv_fused(const float* __restrict__ X,
                                                  const float* __restrict__ LT,
                                                  float* __restrict__ out) {
    __shared__ float wsm[64 * 36];   // 9,216 B

    const int tid = threadIdx.x, lane = tid & 63, wv = tid >> 6;
    int bid = blockIdx.x;
    const int tt = bid & 15;
    const int h = (bid >> 4) & 15;
    const int b = bid >> 8;
    const int T0 = tt * 64;
    const int tlo = T0 + wv * 16 - PADL;   // first x row this wave needs

    // ---- x window into registers: rows tlo .. tlo+45 (uniform guards)
    float xr[47];
#pragma unroll
    for (int rI = 0; rI < 46; ++rI) {
        const int tg = tlo + rI;
        xr[rI] = ((unsigned)tg < TT)
                   ? X[(size_t)(b * TT + tg) * CC + h * RR + lane] : 0.f;
    }
    xr[46] = 0.f;   // pad so k=31 term (weight 0) stays in range

    // ---- softmax: 4 lanes per t (j = lane&3 covers k = 8j..8j+7)
    const int j = lane & 3, a = lane >> 2;
    const int tl = wv * 16 + a;              // t within 64-tile
    const int m = b * TT + T0 + tl;          // global row index
    float v[8];
    float mx = -1e30f;
#pragma unroll
    for (int i = 0; i < 8; ++i) {
        const int kk = j * 8 + i;
        float lv = -1e30f;
        if (kk < KSZ) lv = LT[(size_t)(h * KSZ + kk) * MM + m];
        v[i] = lv; mx = fmaxf(mx, lv);
    }
    mx = fmaxf(mx, __shfl_xor(mx, 1));
    mx = fmaxf(mx, __shfl_xor(mx, 2));
    float s = 0.f;
#pragma unroll
    for (int i = 0; i < 8; ++i) { v[i] = __expf(v[i] - mx); s += v[i]; }
    s += __shfl_xor(s, 1);
    s += __shfl_xor(s, 2);
    const float inv = 1.f / s;
    f32x4 wlo = { v[0] * inv, v[1] * inv, v[2] * inv, v[3] * inv };
    f32x4 whi = { v[4] * inv, v[5] * inv, v[6] * inv, v[7] * inv };
    *(f32x4*)&wsm[tl * 36 + j * 8] = wlo;
    *(f32x4*)&wsm[tl * 36 + j * 8 + 4] = whi;
    __syncthreads();

    // ---- conv: 16 t per lane, all-register x, broadcast w
    float acc[16];
#pragma unroll
    for (int t8 = 0; t8 < 16; ++t8) acc[t8] = 0.f;
#pragma unroll
    for (int t8 = 0; t8 < 16; ++t8) {
        const float* wp = &wsm[(wv * 16 + t8) * 36];
#pragma unroll
        for (int kq = 0; kq < 8; ++kq) {
            const f32x4 w4 = *(const f32x4*)(wp + kq * 4);  // uniform broadcast
#pragma unroll
            for (int jj = 0; jj < 4; ++jj)
                acc[t8] = fmaf(w4[jj], xr[t8 + kq * 4 + jj], acc[t8]);
        }
    }
#pragma unroll
    for (int t8 = 0; t8 < 16; ++t8)
        out[(size_t)(b * TT + T0 + wv * 16 + t8) * CC + h * RR + lane] = acc[t8];
}

// ---------------------------------------------------------------------------
extern "C" void kernel_launch(void* const* d_in, const int* in_sizes, int n_in,
                              void* d_out, int out_size, void* d_ws, size_t ws_size,
                              hipStream_t stream) {
    const float* x = (const float*)d_in[0];
    const float* W = (const float*)d_in[1];
    float* out = (float*)d_out;
    float* LT = (float*)d_ws;   // 8,126,464 B

    gemm_fused<<<NP / 64 * (MM / 64), 256, 0, stream>>>(x, W, LT);
    conv_fused<<<BB * HH * (TT / 64), 256, 0, stream>>>(x, LT, out);
}